// Round 16
// baseline (61.090 us; speedup 1.0000x reference)
//
#include <hip/hip_runtime.h>
#include <hip/hip_bf16.h>

// DLRM forward, bf16-MFMA. R16 = R15 with interact fused into bottom_kernel:
// async gather (global_load_lds) issued before the L0-L2 MFMA chain, raw
// lgkm-only barriers keep it in flight; dots after L2. 5 dispatches:
// wconv, bottom(+gather+dots), top0, top1, top2.
// B=2048, dense 13, emb 26x100000x64, 27 feats -> 351 pairs,
// top MLP 415(->512 pad)->1024->512->256->1 sigmoid.

#define BATCH 2048
#define VOCAB 100000
#define NSPARSE 26
#define NFEA 27
#define NPAIR 351
#define RLD 512            // padded R row stride (415 -> 512, %128==0)

typedef __attribute__((ext_vector_type(8))) __bf16 bf16x8;
typedef __attribute__((ext_vector_type(4))) float f32x4;
typedef __hip_bfloat16 bf16;

#define MFMA16 __builtin_amdgcn_mfma_f32_16x16x32_bf16

#define GLOAD16(g, l)                                                          \
    __builtin_amdgcn_global_load_lds(                                          \
        (const __attribute__((address_space(1))) unsigned int*)(g),            \
        (__attribute__((address_space(3))) unsigned int*)(l), 16, 0, 0)

// raw barrier that does NOT drain vmcnt (keeps async gathers in flight)
#define LGKM_BARRIER()                                                         \
    do {                                                                       \
        asm volatile("s_waitcnt lgkmcnt(0)" ::: "memory");                     \
        __builtin_amdgcn_s_barrier();                                          \
        __builtin_amdgcn_sched_barrier(0);                                     \
    } while (0)

template<int BK>
__device__ __forceinline__ int swz(int row, int s) {
    return (BK == 128) ? (s ^ (row & 15))
         : (BK == 64)  ? (s ^ (row & 7))
                       : (s ^ ((row >> 1) & 3));
}

// ---------------------------------------------------------------------------
// bottom_kernel: fused gather + L0 + L1 + L2 + interaction dots.
// 256 blocks x 8 batch rows (MFMA rows padded to 16).
// LDS ~108 KB -> 1 block/CU (grid == CU count).
// ---------------------------------------------------------------------------
__global__ __launch_bounds__(256) void bottom_kernel(
    const float* __restrict__ dense, const int* __restrict__ cat,
    const float* __restrict__ tables,
    const bf16* __restrict__ bw0t, const float* __restrict__ bb0,
    const bf16* __restrict__ bw1t, const float* __restrict__ bb1,
    const bf16* __restrict__ bw2t, const float* __restrict__ bb2,
    bf16* __restrict__ R)
{
    __shared__ int idxs[8 * NSPARSE];                     //   832 B
    __shared__ __align__(16) float Tg[8 * NSPARSE * 64];  // 53248 B (gather dest)
    __shared__ __align__(16) bf16 ds[16 * 32];            //  1024 B
    __shared__ __align__(16) bf16 h0s[16 * 512];          // 16384 B
    __shared__ __align__(16) bf16 h1s[16 * 256];          //  8192 B
    __shared__ bf16 Tp[8][NFEA][66];                      // 28512 B (padded)

    const int t   = threadIdx.x;
    const int b0  = blockIdx.x * 8;
    const int wid = t >> 6, lane = t & 63;
    const int lr  = lane & 15, q = lane >> 4;

    // stage cat_idx (208 ints, coalesced)
    if (t < 8 * NSPARSE) idxs[t] = cat[b0 * NSPARSE + t];
    __syncthreads();

    // stage dense: rows 0..7 real, 8..15 zero; k-pad 13->32 (loads drain fast)
    for (int idx = t; idx < 16 * 32; idx += 256) {
        const int r = idx >> 5, c = idx & 31;
        const float v = (r < 8 && c < 13) ? dense[(size_t)(b0 + r) * 13 + c] : 0.f;
        ds[r * 32 + swz<32>(r, c >> 3) * 8 + (c & 7)] = __float2bfloat16(v);
    }

    // issue async gather: wave wid, issue i covers 4 row-feats (16 lanes each).
    // 13 issues/wave x 4 waves x 4 rf = 208 row-feats. Stays in flight
    // through the whole L0..L2 chain (raw lgkm barriers never drain vmcnt).
#pragma unroll
    for (int i = 0; i < 13; ++i) {
        const int g  = wid * 13 + i;
        const int rf = g * 4 + (lane >> 4);
        const int r  = rf / NSPARSE, j = rf % NSPARSE;
        (void)r;
        const float* src =
            tables + ((size_t)j * VOCAB + idxs[rf]) * 64 + (lane & 15) * 4;
        GLOAD16(src, (char*)Tg + ((size_t)g * 64 + lane) * 16);
    }

    // zero-pad R[:, 415:512)
    for (int z = t; z < 8 * (RLD - 415); z += 256) {
        const int r = z / (RLD - 415), c = z % (RLD - 415);
        R[(size_t)(b0 + r) * RLD + 415 + c] = __float2bfloat16(0.f);
    }

    LGKM_BARRIER();

    // ---- L0: 4 waves x 128 cols (NREP=8), K=32 ----
    {
        const bf16x8 af = *(const bf16x8*)&ds[lr * 32 + swz<32>(lr, q) * 8];
        const int n0 = wid * 128;
        f32x4 acc[8] = {};
#pragma unroll
        for (int n = 0; n < 8; ++n) {
            const bf16x8 bv =
                *(const bf16x8*)(bw0t + (size_t)(n0 + n * 16 + lr) * 32 + q * 8);
            acc[n] = MFMA16(af, bv, acc[n], 0, 0, 0);
        }
#pragma unroll
        for (int n = 0; n < 8; ++n) {
            const int col = n0 + n * 16 + lr;
            const float bv = bb0[col];
#pragma unroll
            for (int i = 0; i < 4; ++i) {
                const int row = q * 4 + i;
                const float v = fmaxf(acc[n][i] + bv, 0.f);
                h0s[row * 512 + (((col >> 3) ^ (row & 15)) << 3) + (col & 7)] =
                    __float2bfloat16(v);
            }
        }
    }
    LGKM_BARRIER();

    // ---- L1: 4 waves x 64 cols (NREP=4), K=512 ----
    {
        const int n0 = wid * 64;
        const bf16* wp[4];
#pragma unroll
        for (int n = 0; n < 4; ++n)
            wp[n] = bw1t + (size_t)(n0 + n * 16 + lr) * 512 + q * 8;

        f32x4 acc[4] = {};
#pragma unroll 4
        for (int kk = 0; kk < 16; ++kk) {
            const bf16x8 af = *(const bf16x8*)
                &h0s[lr * 512 + (((kk * 4 + q) ^ (lr & 15)) << 3)];
#pragma unroll
            for (int n = 0; n < 4; ++n) {
                const bf16x8 bv = *(const bf16x8*)(wp[n] + kk * 32);
                acc[n] = MFMA16(af, bv, acc[n], 0, 0, 0);
            }
        }
#pragma unroll
        for (int n = 0; n < 4; ++n) {
            const int col = n0 + n * 16 + lr;
            const float bv = bb1[col];
#pragma unroll
            for (int i = 0; i < 4; ++i) {
                const int row = q * 4 + i;
                const float v = fmaxf(acc[n][i] + bv, 0.f);
                h1s[row * 256 + (((col >> 3) ^ (row & 15)) << 3) + (col & 7)] =
                    __float2bfloat16(v);
            }
        }
    }
    LGKM_BARRIER();

    // ---- L2: 4 waves x 16 cols (NREP=1), K=256; bot -> Tp[r][0] + R ----
    {
        const int n0 = wid * 16;
        const bf16* wp = bw2t + (size_t)(n0 + lr) * 256 + q * 8;
        f32x4 acc = {};
#pragma unroll
        for (int kk = 0; kk < 8; ++kk) {
            const bf16x8 af = *(const bf16x8*)
                &h1s[lr * 256 + (((kk * 4 + q) ^ (lr & 15)) << 3)];
            const bf16x8 bv = *(const bf16x8*)(wp + kk * 32);
            acc = MFMA16(af, bv, acc, 0, 0, 0);
        }
        const int col = n0 + lr;
        const float bv = bb2[col];
#pragma unroll
        for (int i = 0; i < 4; ++i) {
            const int row = q * 4 + i;
            if (row < 8) {
                const float v = fmaxf(acc[i] + bv, 0.f);
                const bf16 hv = __float2bfloat16(v);
                Tp[row][0][col] = hv;
                R[(size_t)(b0 + row) * RLD + col] = hv;
            }
        }
    }

    // drain gathers (long since landed) + all LDS writes
    asm volatile("s_waitcnt vmcnt(0) lgkmcnt(0)" ::: "memory");
    __builtin_amdgcn_s_barrier();
    __builtin_amdgcn_sched_barrier(0);

    // repack Tg (f32, linear) -> Tp (bf16, padded stride 66: conflict-free)
    for (int idx = t; idx < 8 * NSPARSE * 64; idx += 256) {
        const int r   = idx / (NSPARSE * 64);
        const int rem = idx % (NSPARSE * 64);
        const int j   = rem >> 6, k = rem & 63;
        Tp[r][j + 1][k] = __float2bfloat16(Tg[idx]);
    }
    LGKM_BARRIER();

    // pairwise dots: 8 x 351 tasks
    for (int task = t; task < 8 * NPAIR; task += 256) {
        const int r = task / NPAIR, p = task % NPAIR;
        int i = (int)((1.0f + sqrtf(1.0f + 8.0f * (float)p)) * 0.5f);
        while (i * (i - 1) / 2 > p) --i;
        while ((i + 1) * i / 2 <= p) ++i;
        const int j = p - i * (i - 1) / 2;
        float s = 0.f;
#pragma unroll 16
        for (int k = 0; k < 64; ++k)
            s += __bfloat162float(Tp[r][i][k]) * __bfloat162float(Tp[r][j][k]);
        R[(size_t)(b0 + r) * RLD + 64 + p] = __float2bfloat16(s);
    }
}

// ---------------------------------------------------------------------------
// bf16 MFMA GEMM (proven): C = relu(A @ Wt^T + bias). Single-buffered.
// ---------------------------------------------------------------------------
template<int BK, int WR, int WC, int MREP, int NREP>
__global__ __launch_bounds__(256) void gemm_bf16(
    const bf16* __restrict__ A, const bf16* __restrict__ Wt,
    const float* __restrict__ bias, bf16* __restrict__ C,
    int M, int N, int K, int ldC)
{
    constexpr int BM    = WR * MREP * 16;
    constexpr int BN    = WC * NREP * 16;
    constexpr int ROWB  = BK * 2;
    constexpr int SLOTS = BK / 8;
    constexpr int KKS   = BK / 32;
    constexpr int PA    = BM * SLOTS / 256;
    constexpr int PB    = BN * SLOTS / 256;

    __shared__ __align__(16) bf16 As[BM * BK];
    __shared__ __align__(16) bf16 Bs[BN * BK];

    const int t   = threadIdx.x;
    const int nbn = N / BN;
    const int bm  = blockIdx.x / nbn;
    const int bn  = blockIdx.x % nbn;
    const int row0 = bm * BM, n0 = bn * BN;

    const int wid  = t >> 6, lane = t & 63;
    const int wr   = wid / WC, wc = wid % WC;
    const int lr   = lane & 15;
    const int q    = lane >> 4;
    const int sslot = t % SLOTS;

    const bf16* Ab[PA];
    const bf16* Bb[PB];
#pragma unroll
    for (int p = 0; p < PA; ++p) {
        const int r = (p * 256 + t) / SLOTS;
        Ab[p] = A + (size_t)(row0 + r) * K + swz<BK>(r, sslot) * 8;
    }
#pragma unroll
    for (int p = 0; p < PB; ++p) {
        const int r = (p * 256 + t) / SLOTS;
        Bb[p] = Wt + (size_t)(n0 + r) * K + swz<BK>(r, sslot) * 8;
    }

    f32x4 acc[MREP][NREP] = {};

    for (int k0 = 0; k0 < K; k0 += BK) {
#pragma unroll
        for (int p = 0; p < PA; ++p)
            GLOAD16(Ab[p] + k0, (char*)As + (p * 256 + t) * 16);
#pragma unroll
        for (int p = 0; p < PB; ++p)
            GLOAD16(Bb[p] + k0, (char*)Bs + (p * 256 + t) * 16);
        __syncthreads();

        bf16x8 af[KKS][MREP], bfr[KKS][NREP];
#pragma unroll
        for (int kk = 0; kk < KKS; ++kk) {
#pragma unroll
            for (int m = 0; m < MREP; ++m) {
                const int r = wr * MREP * 16 + 16 * m + lr;
                af[kk][m] = *(const bf16x8*)((const char*)As + r * ROWB +
                                             swz<BK>(r, kk * 4 + q) * 16);
            }
#pragma unroll
            for (int n = 0; n < NREP; ++n) {
                const int r = wc * NREP * 16 + 16 * n + lr;
                bfr[kk][n] = *(const bf16x8*)((const char*)Bs + r * ROWB +
                                              swz<BK>(r, kk * 4 + q) * 16);
            }
        }
#pragma unroll
        for (int kk = 0; kk < KKS; ++kk)
#pragma unroll
            for (int m = 0; m < MREP; ++m)
#pragma unroll
                for (int n = 0; n < NREP; ++n)
                    acc[m][n] = MFMA16(af[kk][m], bfr[kk][n], acc[m][n], 0, 0, 0);
        __syncthreads();
    }

    // D layout: col = lane&15, row = (lane>>4)*4 + i
#pragma unroll
    for (int n = 0; n < NREP; ++n) {
        const int col = n0 + wc * NREP * 16 + 16 * n + lr;
        const float bv = bias[col];
#pragma unroll
        for (int m = 0; m < MREP; ++m) {
#pragma unroll
            for (int i = 0; i < 4; ++i) {
                const int row = row0 + wr * MREP * 16 + 16 * m + q * 4 + i;
                float v = fmaxf(acc[m][n][i] + bv, 0.f);
                C[(size_t)row * ldC + col] = __float2bfloat16(v);
            }
        }
    }
}

// ---------------------------------------------------------------------------
// top2 + top3 fused (proven): 32 rows x all 256 cols + sigmoid dot.
// ---------------------------------------------------------------------------
__global__ __launch_bounds__(256) void top2_kernel(
    const bf16* __restrict__ A, const bf16* __restrict__ Wt,
    const float* __restrict__ bias, const float* __restrict__ w3,
    const float* __restrict__ b3, float* __restrict__ out)
{
    constexpr int BK = 64, BM = 32, K = 512;
    constexpr int SLOTS = 8, KKS = 2, PA = 1, PB = 8;

    __shared__ __align__(16) bf16 As[BM * BK];
    __shared__ __align__(16) bf16 Bs[256 * BK];
    __shared__ float rsum[BM];

    const int t = threadIdx.x;
    const int row0 = blockIdx.x * BM;
    const int wc = t >> 6, lane = t & 63;
    const int lr = lane & 15, q = lane >> 4;
    const int sslot = t % SLOTS;

    const bf16* Ab[PA];
    const bf16* Bb[PB];
#pragma unroll
    for (int p = 0; p < PA; ++p) {
        const int r = (p * 256 + t) / SLOTS;
        Ab[p] = A + (size_t)(row0 + r) * K + swz<BK>(r, sslot) * 8;
    }
#pragma unroll
    for (int p = 0; p < PB; ++p) {
        const int r = (p * 256 + t) / SLOTS;
        Bb[p] = Wt + (size_t)r * K + swz<BK>(r, sslot) * 8;
    }

    f32x4 acc[2][4] = {};

    for (int k0 = 0; k0 < K; k0 += BK) {
#pragma unroll
        for (int p = 0; p < PA; ++p)
            GLOAD16(Ab[p] + k0, (char*)As + (p * 256 + t) * 16);
#pragma unroll
        for (int p = 0; p < PB; ++p)
            GLOAD16(Bb[p] + k0, (char*)Bs + (p * 256 + t) * 16);
        __syncthreads();

        bf16x8 af[KKS][2], bfr[KKS][4];
#pragma unroll
        for (int kk = 0; kk < KKS; ++kk) {
#pragma unroll
            for (int m = 0; m < 2; ++m) {
                const int r = 16 * m + lr;
                af[kk][m] = *(const bf16x8*)((const char*)As + r * 128 +
                                             swz<BK>(r, kk * 4 + q) * 16);
            }
#pragma unroll
            for (int n = 0; n < 4; ++n) {
                const int r = wc * 64 + 16 * n + lr;
                bfr[kk][n] = *(const bf16x8*)((const char*)Bs + r * 128 +
                                              swz<BK>(r, kk * 4 + q) * 16);
            }
        }
#pragma unroll
        for (int kk = 0; kk < KKS; ++kk)
#pragma unroll
            for (int m = 0; m < 2; ++m)
#pragma unroll
                for (int n = 0; n < 4; ++n)
                    acc[m][n] = MFMA16(af[kk][m], bfr[kk][n], acc[m][n], 0, 0, 0);
        __syncthreads();
    }

    if (t < BM) rsum[t] = 0.f;
    __syncthreads();

#pragma unroll
    for (int m = 0; m < 2; ++m) {
#pragma unroll
        for (int i = 0; i < 4; ++i) {
            float val = 0.f;
#pragma unroll
            for (int n = 0; n < 4; ++n) {
                const int col = wc * 64 + 16 * n + lr;
                val += fmaxf(acc[m][n][i] + bias[col], 0.f) * w3[col];
            }
            val += __shfl_xor(val, 1);
            val += __shfl_xor(val, 2);
            val += __shfl_xor(val, 4);
            val += __shfl_xor(val, 8);
            if (lr == 0) atomicAdd(&rsum[16 * m + q * 4 + i], val);
        }
    }
    __syncthreads();
    if (t < BM)
        out[row0 + t] = 1.f / (1.f + expf(-(rsum[t] + b3[0])));
}

// ---------------------------------------------------------------------------
// Weight convert+transpose: dst[n][kp] = bf16(src[k][n]), zero-pad k>=K.
// ---------------------------------------------------------------------------
struct WConvArgs {
    const float* src[6];
    bf16*        dst[6];
    int K[6], N[6], Kp[6], t0[7];
};

__global__ __launch_bounds__(256) void wconv_kernel(WConvArgs a)
{
    __shared__ float Ts[32][33];
    int w = 0;
    while (w < 5 && (int)blockIdx.x >= a.t0[w + 1]) ++w;
    const int rel = blockIdx.x - a.t0[w];
    const int K = a.K[w], N = a.N[w], Kp = a.Kp[w];
    const int nbn = N >> 5;
    const int tk = rel / nbn, tn = rel % nbn;
    const int tx = threadIdx.x & 31, ty = threadIdx.x >> 5;

    const float* src = a.src[w];
    bf16* dst = a.dst[w];

#pragma unroll
    for (int rr = 0; rr < 4; ++rr) {
        const int k = tk * 32 + ty + rr * 8;
        const int n = tn * 32 + tx;
        Ts[ty + rr * 8][tx] = (k < K) ? src[(size_t)k * N + n] : 0.f;
    }
    __syncthreads();
#pragma unroll
    for (int rr = 0; rr < 4; ++rr) {
        const int n = tn * 32 + ty + rr * 8;
        const int kp = tk * 32 + tx;
        dst[(size_t)n * Kp + kp] = __float2bfloat16(Ts[tx][ty + rr * 8]);
    }
}

// ---------------------------------------------------------------------------
extern "C" void kernel_launch(void* const* d_in, const int* in_sizes, int n_in,
                              void* d_out, int out_size, void* d_ws, size_t ws_size,
                              hipStream_t stream)
{
    const float* dense   = (const float*)d_in[0];
    const int*   cat_idx = (const int*)  d_in[1];
    const float* tables  = (const float*)d_in[2];
    const float* bw0 = (const float*)d_in[3];
    const float* bb0 = (const float*)d_in[4];
    const float* bw1 = (const float*)d_in[5];
    const float* bb1 = (const float*)d_in[6];
    const float* bw2 = (const float*)d_in[7];
    const float* bb2 = (const float*)d_in[8];
    const float* tw0 = (const float*)d_in[9];
    const float* tb0 = (const float*)d_in[10];
    const float* tw1 = (const float*)d_in[11];
    const float* tb1 = (const float*)d_in[12];
    const float* tw2 = (const float*)d_in[13];
    const float* tb2 = (const float*)d_in[14];
    const float* tw3 = (const float*)d_in[15];
    const float* tb3 = (const float*)d_in[16];

    bf16* p = (bf16*)d_ws;
    bf16* R    = p; p += (size_t)BATCH * RLD;
    bf16* r0   = p; p += (size_t)BATCH * 1024;
    bf16* r1   = p; p += (size_t)BATCH * 512;
    bf16* bw0t = p; p += 512 * 32;
    bf16* bw1t = p; p += 256 * 512;
    bf16* bw2t = p; p += 64 * 256;
    bf16* tw0t = p; p += 1024 * RLD;
    bf16* tw1t = p; p += 512 * 1024;
    bf16* tw2t = p; p += 256 * 512;
    float* out = (float*)d_out;

    WConvArgs wa;
    wa.src[0] = bw0;  wa.dst[0] = bw0t; wa.K[0] = 13;   wa.N[0] = 512;  wa.Kp[0] = 32;
    wa.src[1] = bw1;  wa.dst[1] = bw1t; wa.K[1] = 512;  wa.N[1] = 256;  wa.Kp[1] = 512;
    wa.src[2] = bw2;  wa.dst[2] = bw2t; wa.K[2] = 256;  wa.N[2] = 64;   wa.Kp[2] = 256;
    wa.src[3] = tw0;  wa.dst[3] = tw0t; wa.K[3] = 415;  wa.N[3] = 1024; wa.Kp[3] = RLD;
    wa.src[4] = tw1;  wa.dst[4] = tw1t; wa.K[4] = 1024; wa.N[4] = 512;  wa.Kp[4] = 1024;
    wa.src[5] = tw2;  wa.dst[5] = tw2t; wa.K[5] = 512;  wa.N[5] = 256;  wa.Kp[5] = 512;
    int tiles = 0;
    for (int w = 0; w < 6; ++w) {
        wa.t0[w] = tiles;
        tiles += (wa.Kp[w] >> 5) * (wa.N[w] >> 5);
    }
    wa.t0[6] = tiles;

    wconv_kernel<<<tiles, 256, 0, stream>>>(wa);

    // fused bottom MLP + gather + interaction: dense -> ... -> R complete
    bottom_kernel<<<BATCH / 8, 256, 0, stream>>>(
        dense, cat_idx, tables,
        bw0t, bb0, bw1t, bb1, bw2t, bb2, R);

    // top MLP
    gemm_bf16<128, 2, 2, 1, 2><<<(BATCH / 32) * (1024 / 64), 256, 0, stream>>>(
        R, tw0t, tb0, r0, BATCH, 1024, RLD, 1024);
    gemm_bf16<128, 2, 2, 1, 1><<<(BATCH / 32) * (512 / 32), 256, 0, stream>>>(
        r0, tw1t, tb1, r1, BATCH, 512, 1024, 512);
    top2_kernel<<<BATCH / 32, 256, 0, stream>>>(r1, tw2t, tb2, tw3, tb3, out);
}

// Round 17
// 58.950 us; speedup vs baseline: 1.0363x; 1.0363x over previous
//
#include <hip/hip_runtime.h>
#include <hip/hip_bf16.h>

// DLRM forward, bf16-MFMA. R17 = exact revert to R15 (verified best, 59.1us).
// 6 dispatches: wconv, fused-bottom, interact, top0, top1, top2+out.
// B=2048, dense 13, emb 26x100000x64, 27 feats -> 351 pairs,
// top MLP 415(->512 pad)->1024->512->256->1 sigmoid.

#define BATCH 2048
#define VOCAB 100000
#define NSPARSE 26
#define NFEA 27
#define NPAIR 351
#define RLD 512            // padded R row stride (415 -> 512, %128==0)

typedef __attribute__((ext_vector_type(8))) __bf16 bf16x8;
typedef __attribute__((ext_vector_type(4))) float f32x4;
typedef __hip_bfloat16 bf16;

#define MFMA16 __builtin_amdgcn_mfma_f32_16x16x32_bf16

#define GLOAD16(g, l)                                                          \
    __builtin_amdgcn_global_load_lds(                                          \
        (const __attribute__((address_space(1))) unsigned int*)(g),            \
        (__attribute__((address_space(3))) unsigned int*)(l), 16, 0, 0)

template<int BK>
__device__ __forceinline__ int swz(int row, int s) {
    return (BK == 128) ? (s ^ (row & 15))
         : (BK == 64)  ? (s ^ (row & 7))
                       : (s ^ ((row >> 1) & 3));
}

// ---------------------------------------------------------------------------
// bottom_kernel: fused L0+L1+L2 (R14-proven). 256 blocks x 8 rows (pad 16).
// ---------------------------------------------------------------------------
__global__ __launch_bounds__(256) void bottom_kernel(
    const float* __restrict__ dense,
    const bf16* __restrict__ bw0t, const float* __restrict__ bb0,
    const bf16* __restrict__ bw1t, const float* __restrict__ bb1,
    const bf16* __restrict__ bw2t, const float* __restrict__ bb2,
    bf16* __restrict__ R)
{
    __shared__ __align__(16) bf16 ds[16 * 32];
    __shared__ __align__(16) bf16 h0s[16 * 512];
    __shared__ __align__(16) bf16 h1s[16 * 256];

    const int t   = threadIdx.x;
    const int b0  = blockIdx.x * 8;
    const int wid = t >> 6, lane = t & 63;
    const int lr  = lane & 15, q = lane >> 4;

    for (int idx = t; idx < 16 * 32; idx += 256) {
        const int r = idx >> 5, c = idx & 31;
        const float v = (r < 8 && c < 13) ? dense[(size_t)(b0 + r) * 13 + c] : 0.f;
        ds[r * 32 + swz<32>(r, c >> 3) * 8 + (c & 7)] = __float2bfloat16(v);
    }
    __syncthreads();

    // L0: 4 waves x 128 cols (NREP=8), K=32
    {
        const bf16x8 af = *(const bf16x8*)&ds[lr * 32 + swz<32>(lr, q) * 8];
        const int n0 = wid * 128;
        f32x4 acc[8] = {};
#pragma unroll
        for (int n = 0; n < 8; ++n) {
            const bf16x8 bv =
                *(const bf16x8*)(bw0t + (size_t)(n0 + n * 16 + lr) * 32 + q * 8);
            acc[n] = MFMA16(af, bv, acc[n], 0, 0, 0);
        }
#pragma unroll
        for (int n = 0; n < 8; ++n) {
            const int col = n0 + n * 16 + lr;
            const float bv = bb0[col];
#pragma unroll
            for (int i = 0; i < 4; ++i) {
                const int row = q * 4 + i;
                const float v = fmaxf(acc[n][i] + bv, 0.f);
                h0s[row * 512 + (((col >> 3) ^ (row & 15)) << 3) + (col & 7)] =
                    __float2bfloat16(v);
            }
        }
    }
    __syncthreads();

    // L1: 4 waves x 64 cols (NREP=4), K=512
    {
        const int n0 = wid * 64;
        const bf16* wp[4];
#pragma unroll
        for (int n = 0; n < 4; ++n)
            wp[n] = bw1t + (size_t)(n0 + n * 16 + lr) * 512 + q * 8;

        f32x4 acc[4] = {};
#pragma unroll 4
        for (int kk = 0; kk < 16; ++kk) {
            const bf16x8 af = *(const bf16x8*)
                &h0s[lr * 512 + (((kk * 4 + q) ^ (lr & 15)) << 3)];
#pragma unroll
            for (int n = 0; n < 4; ++n) {
                const bf16x8 bv = *(const bf16x8*)(wp[n] + kk * 32);
                acc[n] = MFMA16(af, bv, acc[n], 0, 0, 0);
            }
        }
#pragma unroll
        for (int n = 0; n < 4; ++n) {
            const int col = n0 + n * 16 + lr;
            const float bv = bb1[col];
#pragma unroll
            for (int i = 0; i < 4; ++i) {
                const int row = q * 4 + i;
                const float v = fmaxf(acc[n][i] + bv, 0.f);
                h1s[row * 256 + (((col >> 3) ^ (row & 15)) << 3) + (col & 7)] =
                    __float2bfloat16(v);
            }
        }
    }
    __syncthreads();

    // L2: 4 waves x 16 cols (NREP=1), K=256
    {
        const int n0 = wid * 16;
        const bf16* wp = bw2t + (size_t)(n0 + lr) * 256 + q * 8;
        f32x4 acc = {};
#pragma unroll
        for (int kk = 0; kk < 8; ++kk) {
            const bf16x8 af = *(const bf16x8*)
                &h1s[lr * 256 + (((kk * 4 + q) ^ (lr & 15)) << 3)];
            const bf16x8 bv = *(const bf16x8*)(wp + kk * 32);
            acc = MFMA16(af, bv, acc, 0, 0, 0);
        }
        const int col = n0 + lr;
        const float bv = bb2[col];
#pragma unroll
        for (int i = 0; i < 4; ++i) {
            const int row = q * 4 + i;
            if (row < 8) {
                const float v = fmaxf(acc[i] + bv, 0.f);
                R[(size_t)(b0 + row) * RLD + col] = __float2bfloat16(v);
            }
        }
    }
}

// ---------------------------------------------------------------------------
// bf16 MFMA GEMM (proven): C = relu(A @ Wt^T + bias). Single-buffered.
// ---------------------------------------------------------------------------
template<int BK, int WR, int WC, int MREP, int NREP>
__global__ __launch_bounds__(256) void gemm_bf16(
    const bf16* __restrict__ A, const bf16* __restrict__ Wt,
    const float* __restrict__ bias, bf16* __restrict__ C,
    int M, int N, int K, int ldC)
{
    constexpr int BM    = WR * MREP * 16;
    constexpr int BN    = WC * NREP * 16;
    constexpr int ROWB  = BK * 2;
    constexpr int SLOTS = BK / 8;
    constexpr int KKS   = BK / 32;
    constexpr int PA    = BM * SLOTS / 256;
    constexpr int PB    = BN * SLOTS / 256;

    __shared__ __align__(16) bf16 As[BM * BK];
    __shared__ __align__(16) bf16 Bs[BN * BK];

    const int t   = threadIdx.x;
    const int nbn = N / BN;
    const int bm  = blockIdx.x / nbn;
    const int bn  = blockIdx.x % nbn;
    const int row0 = bm * BM, n0 = bn * BN;

    const int wid  = t >> 6, lane = t & 63;
    const int wr   = wid / WC, wc = wid % WC;
    const int lr   = lane & 15;
    const int q    = lane >> 4;
    const int sslot = t % SLOTS;

    const bf16* Ab[PA];
    const bf16* Bb[PB];
#pragma unroll
    for (int p = 0; p < PA; ++p) {
        const int r = (p * 256 + t) / SLOTS;
        Ab[p] = A + (size_t)(row0 + r) * K + swz<BK>(r, sslot) * 8;
    }
#pragma unroll
    for (int p = 0; p < PB; ++p) {
        const int r = (p * 256 + t) / SLOTS;
        Bb[p] = Wt + (size_t)(n0 + r) * K + swz<BK>(r, sslot) * 8;
    }

    f32x4 acc[MREP][NREP] = {};

    for (int k0 = 0; k0 < K; k0 += BK) {
#pragma unroll
        for (int p = 0; p < PA; ++p)
            GLOAD16(Ab[p] + k0, (char*)As + (p * 256 + t) * 16);
#pragma unroll
        for (int p = 0; p < PB; ++p)
            GLOAD16(Bb[p] + k0, (char*)Bs + (p * 256 + t) * 16);
        __syncthreads();

        bf16x8 af[KKS][MREP], bfr[KKS][NREP];
#pragma unroll
        for (int kk = 0; kk < KKS; ++kk) {
#pragma unroll
            for (int m = 0; m < MREP; ++m) {
                const int r = wr * MREP * 16 + 16 * m + lr;
                af[kk][m] = *(const bf16x8*)((const char*)As + r * ROWB +
                                             swz<BK>(r, kk * 4 + q) * 16);
            }
#pragma unroll
            for (int n = 0; n < NREP; ++n) {
                const int r = wc * NREP * 16 + 16 * n + lr;
                bfr[kk][n] = *(const bf16x8*)((const char*)Bs + r * ROWB +
                                              swz<BK>(r, kk * 4 + q) * 16);
            }
        }
#pragma unroll
        for (int kk = 0; kk < KKS; ++kk)
#pragma unroll
            for (int m = 0; m < MREP; ++m)
#pragma unroll
                for (int n = 0; n < NREP; ++n)
                    acc[m][n] = MFMA16(af[kk][m], bfr[kk][n], acc[m][n], 0, 0, 0);
        __syncthreads();
    }

    // D layout: col = lane&15, row = (lane>>4)*4 + i
#pragma unroll
    for (int n = 0; n < NREP; ++n) {
        const int col = n0 + wc * NREP * 16 + 16 * n + lr;
        const float bv = bias[col];
#pragma unroll
        for (int m = 0; m < MREP; ++m) {
#pragma unroll
            for (int i = 0; i < 4; ++i) {
                const int row = row0 + wr * MREP * 16 + 16 * m + q * 4 + i;
                float v = fmaxf(acc[m][n][i] + bv, 0.f);
                C[(size_t)row * ldC + col] = __float2bfloat16(v);
            }
        }
    }
}

// ---------------------------------------------------------------------------
// top2 + top3 fused (proven): 32 rows x all 256 cols + sigmoid dot.
// ---------------------------------------------------------------------------
__global__ __launch_bounds__(256) void top2_kernel(
    const bf16* __restrict__ A, const bf16* __restrict__ Wt,
    const float* __restrict__ bias, const float* __restrict__ w3,
    const float* __restrict__ b3, float* __restrict__ out)
{
    constexpr int BK = 64, BM = 32, K = 512;
    constexpr int SLOTS = 8, KKS = 2, PA = 1, PB = 8;

    __shared__ __align__(16) bf16 As[BM * BK];
    __shared__ __align__(16) bf16 Bs[256 * BK];
    __shared__ float rsum[BM];

    const int t = threadIdx.x;
    const int row0 = blockIdx.x * BM;
    const int wc = t >> 6, lane = t & 63;
    const int lr = lane & 15, q = lane >> 4;
    const int sslot = t % SLOTS;

    const bf16* Ab[PA];
    const bf16* Bb[PB];
#pragma unroll
    for (int p = 0; p < PA; ++p) {
        const int r = (p * 256 + t) / SLOTS;
        Ab[p] = A + (size_t)(row0 + r) * K + swz<BK>(r, sslot) * 8;
    }
#pragma unroll
    for (int p = 0; p < PB; ++p) {
        const int r = (p * 256 + t) / SLOTS;
        Bb[p] = Wt + (size_t)r * K + swz<BK>(r, sslot) * 8;
    }

    f32x4 acc[2][4] = {};

    for (int k0 = 0; k0 < K; k0 += BK) {
#pragma unroll
        for (int p = 0; p < PA; ++p)
            GLOAD16(Ab[p] + k0, (char*)As + (p * 256 + t) * 16);
#pragma unroll
        for (int p = 0; p < PB; ++p)
            GLOAD16(Bb[p] + k0, (char*)Bs + (p * 256 + t) * 16);
        __syncthreads();

        bf16x8 af[KKS][2], bfr[KKS][4];
#pragma unroll
        for (int kk = 0; kk < KKS; ++kk) {
#pragma unroll
            for (int m = 0; m < 2; ++m) {
                const int r = 16 * m + lr;
                af[kk][m] = *(const bf16x8*)((const char*)As + r * 128 +
                                             swz<BK>(r, kk * 4 + q) * 16);
            }
#pragma unroll
            for (int n = 0; n < 4; ++n) {
                const int r = wc * 64 + 16 * n + lr;
                bfr[kk][n] = *(const bf16x8*)((const char*)Bs + r * 128 +
                                              swz<BK>(r, kk * 4 + q) * 16);
            }
        }
#pragma unroll
        for (int kk = 0; kk < KKS; ++kk)
#pragma unroll
            for (int m = 0; m < 2; ++m)
#pragma unroll
                for (int n = 0; n < 4; ++n)
                    acc[m][n] = MFMA16(af[kk][m], bfr[kk][n], acc[m][n], 0, 0, 0);
        __syncthreads();
    }

    if (t < BM) rsum[t] = 0.f;
    __syncthreads();

#pragma unroll
    for (int m = 0; m < 2; ++m) {
#pragma unroll
        for (int i = 0; i < 4; ++i) {
            float val = 0.f;
#pragma unroll
            for (int n = 0; n < 4; ++n) {
                const int col = wc * 64 + 16 * n + lr;
                val += fmaxf(acc[m][n][i] + bias[col], 0.f) * w3[col];
            }
            val += __shfl_xor(val, 1);
            val += __shfl_xor(val, 2);
            val += __shfl_xor(val, 4);
            val += __shfl_xor(val, 8);
            if (lr == 0) atomicAdd(&rsum[16 * m + q * 4 + i], val);
        }
    }
    __syncthreads();
    if (t < BM)
        out[row0 + t] = 1.f / (1.f + expf(-(rsum[t] + b3[0])));
}

// ---------------------------------------------------------------------------
// Weight convert+transpose: dst[n][kp] = bf16(src[k][n]), zero-pad k>=K.
// ---------------------------------------------------------------------------
struct WConvArgs {
    const float* src[6];
    bf16*        dst[6];
    int K[6], N[6], Kp[6], t0[7];
};

__global__ __launch_bounds__(256) void wconv_kernel(WConvArgs a)
{
    __shared__ float Ts[32][33];
    int w = 0;
    while (w < 5 && (int)blockIdx.x >= a.t0[w + 1]) ++w;
    const int rel = blockIdx.x - a.t0[w];
    const int K = a.K[w], N = a.N[w], Kp = a.Kp[w];
    const int nbn = N >> 5;
    const int tk = rel / nbn, tn = rel % nbn;
    const int tx = threadIdx.x & 31, ty = threadIdx.x >> 5;

    const float* src = a.src[w];
    bf16* dst = a.dst[w];

#pragma unroll
    for (int rr = 0; rr < 4; ++rr) {
        const int k = tk * 32 + ty + rr * 8;
        const int n = tn * 32 + tx;
        Ts[ty + rr * 8][tx] = (k < K) ? src[(size_t)k * N + n] : 0.f;
    }
    __syncthreads();
#pragma unroll
    for (int rr = 0; rr < 4; ++rr) {
        const int n = tn * 32 + ty + rr * 8;
        const int kp = tk * 32 + tx;
        dst[(size_t)n * Kp + kp] = __float2bfloat16(Ts[tx][ty + rr * 8]);
    }
}

// ---------------------------------------------------------------------------
// Embedding gather + pairwise dots. One block per batch row (proven).
// ---------------------------------------------------------------------------
__global__ __launch_bounds__(256) void interact_kernel(
    const int* __restrict__ cat_idx, const float* __restrict__ tables,
    bf16* __restrict__ R)
{
    __shared__ float T[NFEA][64 + 1];

    const int b    = blockIdx.x;
    const int t    = threadIdx.x;
    const int g    = t >> 6;
    const int lane = t & 63;
    bf16* Rrow = R + (size_t)b * RLD;

    for (int f = g; f < NFEA; f += 4) {
        if (f == 0) {
            T[0][lane] = __bfloat162float(Rrow[lane]);
        } else {
            const int j   = f - 1;
            const int idx = cat_idx[b * NSPARSE + j];
            T[f][lane] = tables[((size_t)j * VOCAB + idx) * 64 + lane];
        }
    }
    __syncthreads();

    if (t < RLD - 415) Rrow[415 + t] = __float2bfloat16(0.f);

    for (int p = t; p < NPAIR; p += 256) {
        int i = (int)((1.0f + sqrtf(1.0f + 8.0f * (float)p)) * 0.5f);
        while (i * (i - 1) / 2 > p) --i;
        while ((i + 1) * i / 2 <= p) ++i;
        const int j = p - i * (i - 1) / 2;
        float s = 0.f;
#pragma unroll 16
        for (int k = 0; k < 64; ++k) s += T[i][k] * T[j][k];
        Rrow[64 + p] = __float2bfloat16(s);
    }
}

// ---------------------------------------------------------------------------
extern "C" void kernel_launch(void* const* d_in, const int* in_sizes, int n_in,
                              void* d_out, int out_size, void* d_ws, size_t ws_size,
                              hipStream_t stream)
{
    const float* dense   = (const float*)d_in[0];
    const int*   cat_idx = (const int*)  d_in[1];
    const float* tables  = (const float*)d_in[2];
    const float* bw0 = (const float*)d_in[3];
    const float* bb0 = (const float*)d_in[4];
    const float* bw1 = (const float*)d_in[5];
    const float* bb1 = (const float*)d_in[6];
    const float* bw2 = (const float*)d_in[7];
    const float* bb2 = (const float*)d_in[8];
    const float* tw0 = (const float*)d_in[9];
    const float* tb0 = (const float*)d_in[10];
    const float* tw1 = (const float*)d_in[11];
    const float* tb1 = (const float*)d_in[12];
    const float* tw2 = (const float*)d_in[13];
    const float* tb2 = (const float*)d_in[14];
    const float* tw3 = (const float*)d_in[15];
    const float* tb3 = (const float*)d_in[16];

    bf16* p = (bf16*)d_ws;
    bf16* R    = p; p += (size_t)BATCH * RLD;
    bf16* r0   = p; p += (size_t)BATCH * 1024;
    bf16* r1   = p; p += (size_t)BATCH * 512;
    bf16* bw0t = p; p += 512 * 32;
    bf16* bw1t = p; p += 256 * 512;
    bf16* bw2t = p; p += 64 * 256;
    bf16* tw0t = p; p += 1024 * RLD;
    bf16* tw1t = p; p += 512 * 1024;
    bf16* tw2t = p; p += 256 * 512;
    float* out = (float*)d_out;

    WConvArgs wa;
    wa.src[0] = bw0;  wa.dst[0] = bw0t; wa.K[0] = 13;   wa.N[0] = 512;  wa.Kp[0] = 32;
    wa.src[1] = bw1;  wa.dst[1] = bw1t; wa.K[1] = 512;  wa.N[1] = 256;  wa.Kp[1] = 512;
    wa.src[2] = bw2;  wa.dst[2] = bw2t; wa.K[2] = 256;  wa.N[2] = 64;   wa.Kp[2] = 256;
    wa.src[3] = tw0;  wa.dst[3] = tw0t; wa.K[3] = 415;  wa.N[3] = 1024; wa.Kp[3] = RLD;
    wa.src[4] = tw1;  wa.dst[4] = tw1t; wa.K[4] = 1024; wa.N[4] = 512;  wa.Kp[4] = 1024;
    wa.src[5] = tw2;  wa.dst[5] = tw2t; wa.K[5] = 512;  wa.N[5] = 256;  wa.Kp[5] = 512;
    int tiles = 0;
    for (int w = 0; w < 6; ++w) {
        wa.t0[w] = tiles;
        tiles += (wa.Kp[w] >> 5) * (wa.N[w] >> 5);
    }
    wa.t0[6] = tiles;

    wconv_kernel<<<tiles, 256, 0, stream>>>(wa);

    // fused bottom MLP: dense -> h0 -> h1 -> bot -> R[:, :64]
    bottom_kernel<<<BATCH / 8, 256, 0, stream>>>(
        dense, bw0t, bb0, bw1t, bb1, bw2t, bb2, R);

    interact_kernel<<<BATCH, 256, 0, stream>>>(cat_idx, tables, R);

    // top MLP: top0 BM=32 -> 1024 blocks; top1 BM=32/BN=32 -> 1024 blocks
    gemm_bf16<128, 2, 2, 1, 2><<<(BATCH / 32) * (1024 / 64), 256, 0, stream>>>(
        R, tw0t, tb0, r0, BATCH, 1024, RLD, 1024);
    gemm_bf16<128, 2, 2, 1, 1><<<(BATCH / 32) * (512 / 32), 256, 0, stream>>>(
        r0, tw1t, tb1, r1, BATCH, 512, 1024, 512);
    top2_kernel<<<BATCH / 32, 256, 0, stream>>>(r1, tw2t, tb2, tw3, tb3, out);
}